// Round 1
// 1666.617 us; speedup vs baseline: 1.3848x; 1.3848x over previous
//
#include <hip/hip_runtime.h>
#include <hip/hip_bf16.h>

// ---- problem dims ----
#define BB     2
#define LL     1024
#define BL     (BB*LL)      // 2048 rows
#define BDIM   768
#define EDIM   1536
#define NST    16
#define DDELTA 48
#define DDPAD  64
#define DCONV  4
#define VOCAB  50280
#define NLAYERS 2

// ---- chunked scan params ----
#define CCH    16                 // chunks over L
#define TCH    (LL/CCH)           // 64 steps per chunk
#define BEN    (BB*EDIM*NST)      // 49152 recurrence lanes

typedef __hip_bfloat16 bf16;
typedef short short8 __attribute__((ext_vector_type(8)));
typedef float floatx4 __attribute__((ext_vector_type(4)));

static __device__ __forceinline__ float bf2f(bf16 v){ return __bfloat162float(v); }
static __device__ __forceinline__ bf16  f2bf(float v){ return __float2bfloat16(v); }

// ---- fp32 -> bf16 conversion (for MFMA weight operands) ----
__global__ void k_cvt(const float* __restrict__ src, bf16* __restrict__ dst) {
  int idx = blockIdx.x*256 + threadIdx.x;
  dst[idx] = f2bf(src[idx]);
}

// ---- embedding gather: resid[bl,d] = emb[tok[bl],d] ----
__global__ void k_embed(const int* __restrict__ tok, const float* __restrict__ emb,
                        float* __restrict__ resid) {
  int idx = blockIdx.x*256 + threadIdx.x;       // BL*BDIM total, exact
  int bl = idx / BDIM, d = idx % BDIM;
  resid[idx] = emb[(size_t)tok[bl]*BDIM + d];
}

// ---- rmsnorm row kernel: out_bf16[m,:] = resid[m,:]*rsqrt(mean sq + 1e-5)*w ----
__global__ __launch_bounds__(256) void k_rmsnorm(const float* __restrict__ resid,
                        const float* __restrict__ w, bf16* __restrict__ out) {
  int m = blockIdx.x, tid = threadIdx.x;
  const float* row = resid + (size_t)m*BDIM;
  float ss = 0.f;
  for (int d = tid; d < BDIM; d += 256) { float v = row[d]; ss += v*v; }
  for (int off = 32; off; off >>= 1) ss += __shfl_down(ss, off);
  __shared__ float red[4];
  if ((tid & 63) == 0) red[tid>>6] = ss;
  __syncthreads();
  float rstd = rsqrtf((red[0]+red[1]+red[2]+red[3]) / (float)BDIM + 1e-5f);
  for (int d = tid; d < BDIM; d += 256)
    out[(size_t)m*BDIM + d] = f2bf(row[d]*rstd*w[d]);
}

// ---- MFMA GEMM: C[M,N] = A[M,K](bf16) @ W[N,K](bf16)^T ----
// 128x128 tile, 256 thr = 4 waves (2x2 of 64x64), BK=32, 16x16x32 bf16 MFMA.
// W rows clamped to N-1 (reads valid mem), stores masked n<N.
template<bool OUT_BF16>
__global__ __launch_bounds__(256) void k_gemm(const bf16* __restrict__ A,
      const bf16* __restrict__ W, void* __restrict__ Cp, int N, int K) {
  __shared__ alignas(16) bf16 As[128*32];
  __shared__ alignas(16) bf16 Bs[128*32];
  const int m0 = blockIdx.y * 128, n0 = blockIdx.x * 128;
  const int tid = threadIdx.x, lane = tid & 63, wave = tid >> 6;
  const int wm = (wave >> 1) * 64, wn = (wave & 1) * 64;
  const int r = tid >> 2, c = tid & 3;          // staging: 64 rows x 4 16B-chunks
  const int mr = lane & 15, q = lane >> 4;      // fragment lane decomposition
  floatx4 acc[4][4] = {};

  int wr0 = n0 + r;       if (wr0 >= N) wr0 = N - 1;
  int wr1 = n0 + 64 + r;  if (wr1 >= N) wr1 = N - 1;

  for (int k0 = 0; k0 < K; k0 += 32) {
    int4 a0 = *reinterpret_cast<const int4*>(A + (size_t)(m0 + r     )*K + k0 + c*8);
    int4 a1 = *reinterpret_cast<const int4*>(A + (size_t)(m0 + 64 + r)*K + k0 + c*8);
    int4 b0 = *reinterpret_cast<const int4*>(W + (size_t)wr0*K + k0 + c*8);
    int4 b1 = *reinterpret_cast<const int4*>(W + (size_t)wr1*K + k0 + c*8);
    __syncthreads();     // previous iter's ds_reads done before overwrite
    *reinterpret_cast<int4*>(&As[(r     )*32 + c*8]) = a0;
    *reinterpret_cast<int4*>(&As[(64 + r)*32 + c*8]) = a1;
    *reinterpret_cast<int4*>(&Bs[(r     )*32 + c*8]) = b0;
    *reinterpret_cast<int4*>(&Bs[(64 + r)*32 + c*8]) = b1;
    __syncthreads();
    short8 af[4], bfr[4];
    #pragma unroll
    for (int i = 0; i < 4; i++)
      af[i]  = *reinterpret_cast<const short8*>(&As[(wm + i*16 + mr)*32 + q*8]);
    #pragma unroll
    for (int j = 0; j < 4; j++)
      bfr[j] = *reinterpret_cast<const short8*>(&Bs[(wn + j*16 + mr)*32 + q*8]);
    #pragma unroll
    for (int i = 0; i < 4; i++)
      #pragma unroll
      for (int j = 0; j < 4; j++)
        acc[i][j] = __builtin_amdgcn_mfma_f32_16x16x32_bf16(af[i], bfr[j], acc[i][j], 0, 0, 0);
  }
  // epilogue: C/D layout col=lane&15, row=quad*4+reg
  #pragma unroll
  for (int i = 0; i < 4; i++)
    #pragma unroll
    for (int j = 0; j < 4; j++)
      #pragma unroll
      for (int rg = 0; rg < 4; rg++) {
        int m = m0 + wm + i*16 + q*4 + rg;
        int n = n0 + wn + j*16 + mr;
        if (n < N) {
          float v = acc[i][j][rg];
          if (OUT_BF16) ((bf16*)Cp)[(size_t)m*N + n] = f2bf(v);
          else          ((float*)Cp)[(size_t)m*N + n] = v;
        }
      }
}

// ---- depthwise causal conv (k=4) + bias + silu ----
__global__ void k_conv(const float* __restrict__ xi, const float* __restrict__ cw,
                       const float* __restrict__ cb, float* __restrict__ xc) {
  int idx = blockIdx.x*256 + threadIdx.x;       // BL*EDIM, exact
  int e = idx % EDIM, bl = idx / EDIM, l = bl % LL;
  float acc = cb[e];
  #pragma unroll
  for (int k = 0; k < DCONV; k++) {
    int ls = l - (DCONV-1) + k;
    if (ls >= 0) acc += xi[(size_t)(bl + ls - l)*EDIM + e] * cw[e*DCONV + k];
  }
  xc[idx] = acc / (1.f + expf(-acc));
}

// ---- skinny GEMM: d1[m,0:64] = xc[m,:] @ Wd1[48,E]^T  (cols 48..63 = 0), bf16 out ----
__global__ __launch_bounds__(256) void k_d1(const float* __restrict__ xc,
      const float* __restrict__ wd1, bf16* __restrict__ d1) {
  int m = blockIdx.x, tid = threadIdx.x;
  __shared__ float xrow[EDIM];
  for (int k = tid; k < EDIM; k += 256) xrow[k] = xc[(size_t)m*EDIM + k];
  __syncthreads();
  int wave = tid >> 6, lane = tid & 63;
  for (int n = wave; n < DDPAD; n += 4) {
    float s = 0.f;
    if (n < DDELTA) {
      const float* wr = wd1 + (size_t)n*EDIM;
      for (int k = lane; k < EDIM; k += 64) s += xrow[k]*wr[k];
      for (int off = 32; off; off >>= 1) s += __shfl_down(s, off);
    }
    if (lane == 0) d1[(size_t)m*DDPAD + n] = f2bf(s);
  }
}

// ---- pad + cvt Wd2 [E,48] fp32 -> [E,64] bf16 ----
__global__ void k_padw(const float* __restrict__ wsrc, bf16* __restrict__ wp) {
  int idx = blockIdx.x*256 + threadIdx.x;       // EDIM*64
  int e = idx >> 6, cc = idx & 63;
  wp[idx] = (cc < DDELTA) ? f2bf(wsrc[(size_t)e*DDELTA + cc]) : f2bf(0.f);
}

// ---- softplus(x + b[e]) in place ----
__global__ void k_softplus(float* __restrict__ d, const float* __restrict__ b) {
  int idx = blockIdx.x*256 + threadIdx.x;       // BL*EDIM
  int e = idx % EDIM;
  float v = d[idx] + b[e];
  d[idx] = fmaxf(v, 0.f) + log1pf(expf(-fabsf(v)));
}

// ---- skinny GEMM: Bm/Cm[m,0:16] = xc[m,:] @ {WB,WC}[16,E]^T ----
__global__ __launch_bounds__(256) void k_bc(const float* __restrict__ xc,
    const float* __restrict__ wb, const float* __restrict__ wc,
    float* __restrict__ Bm, float* __restrict__ Cm) {
  int m = blockIdx.x, tid = threadIdx.x;
  __shared__ float xrow[EDIM];
  for (int k = tid; k < EDIM; k += 256) xrow[k] = xc[(size_t)m*EDIM + k];
  __syncthreads();
  int wave = tid >> 6, lane = tid & 63;
  for (int n = wave; n < 32; n += 4) {
    const float* wr = (n < NST) ? wb + (size_t)n*EDIM : wc + (size_t)(n-NST)*EDIM;
    float s = 0.f;
    for (int k = lane; k < EDIM; k += 64) s += xrow[k]*wr[k];
    for (int off = 32; off; off >>= 1) s += __shfl_down(s, off);
    if (lane == 0) {
      if (n < NST) Bm[(size_t)m*NST + n]       = s;
      else         Cm[(size_t)m*NST + (n-NST)] = s;
    }
  }
}

// ---- chunked selective scan ----
// Recurrence h_t = a_t h_{t-1} + b_t (a_t = exp(delta_t*A[e,n])) is associative.
// Split L into CCH chunks of TCH; pass1 scans each chunk from h=0 emitting
// (P = prod a_t, H = local end state); tiny serial fix-up combines chunk carries;
// pass2 rescans each chunk from its true h_in and reduces y over n.
// Parallelism: 192 blocks -> 3072 blocks (full occupancy vs 0.75 waves/SIMD).

// thread map (all scan kernels): n = tid&15, el = tid>>4 (16 e per block)
// block map: bx -> et (E/16), c (CCH), b (BB)

__global__ __launch_bounds__(256) void k_scan1(const float* __restrict__ delta,
    const float* __restrict__ xc, const float* __restrict__ Bm,
    const float* __restrict__ a_log, float* __restrict__ Pbuf,
    float* __restrict__ Hbuf) {
  int tid = threadIdx.x;
  int n = tid & 15, el = tid >> 4;
  int bx = blockIdx.x;
  int et = bx % (EDIM/16); bx /= (EDIM/16);
  int c = bx % CCH, b = bx / CCH;
  int e = et*16 + el;
  float Aen = -__expf(a_log[(size_t)e*NST + n]);
  const float* dp = delta + ((size_t)b*LL + (size_t)c*TCH)*EDIM + e;
  const float* xp = xc    + ((size_t)b*LL + (size_t)c*TCH)*EDIM + e;
  const float* bp = Bm    + ((size_t)b*LL + (size_t)c*TCH)*NST + n;
  float h = 0.f, p = 1.f;
  #pragma unroll 4
  for (int t = 0; t < TCH; t++) {
    float dl = dp[(size_t)t*EDIM];
    float xv = xp[(size_t)t*EDIM];
    float bv = bp[t*NST];
    float a = __expf(dl*Aen);
    h = a*h + dl*bv*xv;
    p *= a;
  }
  size_t ben = ((size_t)b*EDIM + e)*NST + n;
  Pbuf[(size_t)c*BEN + ben] = p;
  Hbuf[(size_t)c*BEN + ben] = h;
}

__global__ __launch_bounds__(256) void k_scanfix(const float* __restrict__ Pbuf,
    const float* __restrict__ Hbuf, float* __restrict__ Hin) {
  int ben = blockIdx.x*256 + threadIdx.x;       // BEN total, exact
  float h = 0.f;
  #pragma unroll
  for (int c = 0; c < CCH; c++) {
    Hin[(size_t)c*BEN + ben] = h;
    h = Pbuf[(size_t)c*BEN + ben]*h + Hbuf[(size_t)c*BEN + ben];
  }
}

__global__ __launch_bounds__(256) void k_scan2(const float* __restrict__ delta,
    const float* __restrict__ xc, const float* __restrict__ Bm,
    const float* __restrict__ Cm, const float* __restrict__ a_log,
    const float* __restrict__ Hin, float* __restrict__ y) {
  int tid = threadIdx.x;
  int n = tid & 15, el = tid >> 4;
  int bx = blockIdx.x;
  int et = bx % (EDIM/16); bx /= (EDIM/16);
  int c = bx % CCH, b = bx / CCH;
  int e = et*16 + el;
  float Aen = -__expf(a_log[(size_t)e*NST + n]);
  const float* dp = delta + ((size_t)b*LL + (size_t)c*TCH)*EDIM + e;
  const float* xp = xc    + ((size_t)b*LL + (size_t)c*TCH)*EDIM + e;
  const float* bp = Bm    + ((size_t)b*LL + (size_t)c*TCH)*NST + n;
  const float* cp = Cm    + ((size_t)b*LL + (size_t)c*TCH)*NST + n;
  float* yp = y + ((size_t)b*LL + (size_t)c*TCH)*EDIM + e;
  size_t ben = ((size_t)b*EDIM + e)*NST + n;
  float h = Hin[(size_t)c*BEN + ben];
  #pragma unroll 4
  for (int t = 0; t < TCH; t++) {
    float dl = dp[(size_t)t*EDIM];
    float xv = xp[(size_t)t*EDIM];
    float bv = bp[t*NST];
    float cv = cp[t*NST];
    h = __expf(dl*Aen)*h + dl*bv*xv;
    float p = h*cv;
    p += __shfl_xor(p, 1); p += __shfl_xor(p, 2);
    p += __shfl_xor(p, 4); p += __shfl_xor(p, 8);
    if (n == 0) yp[(size_t)t*EDIM] = p;
  }
}

// ---- y2 = (y + xc*wd[e]) * silu(skip), bf16 out ----
__global__ void k_ymix(const float* __restrict__ y, const float* __restrict__ xc,
    const float* __restrict__ skip, const float* __restrict__ wd, bf16* __restrict__ y2) {
  int idx = blockIdx.x*256 + threadIdx.x;       // BL*EDIM
  int e = idx % EDIM;
  float s = skip[idx];
  y2[idx] = f2bf((y[idx] + xc[idx]*wd[e]) * (s / (1.f + expf(-s))));
}

// ---- resid += d ----
__global__ void k_add(float* __restrict__ resid, const float* __restrict__ d) {
  int idx = blockIdx.x*256 + threadIdx.x;
  resid[idx] += d[idx];
}

extern "C" void kernel_launch(void* const* d_in, const int* in_sizes, int n_in,
                              void* d_out, int out_size, void* d_ws, size_t ws_size,
                              hipStream_t stream) {
  const int*   tokens = (const int*)  d_in[0];
  const float* emb    = (const float*)d_in[1];
  const float* norm_w = (const float*)d_in[2];
  const float* skip_w = (const float*)d_in[3];
  const float* in_w   = (const float*)d_in[4];
  const float* conv_w = (const float*)d_in[5];
  const float* conv_b = (const float*)d_in[6];
  const float* Wd1    = (const float*)d_in[7];
  const float* Wd2w   = (const float*)d_in[8];
  const float* Wd2b   = (const float*)d_in[9];
  const float* WBw    = (const float*)d_in[10];
  const float* WCw    = (const float*)d_in[11];
  const float* A_log  = (const float*)d_in[12];
  const float* W_D    = (const float*)d_in[13];
  const float* out_w  = (const float*)d_in[14];
  const float* fnw    = (const float*)d_in[15];
  const float* lm_w   = (const float*)d_in[16];
  float* out = (float*)d_out;

  // workspace layout (256B-aligned chunks)
  char* wsp = (char*)d_ws;
  auto alloc = [&](size_t bytes) { char* p = wsp; wsp += (bytes + 255) & ~(size_t)255; return p; };
  float* resid = (float*)alloc((size_t)BL*BDIM*4);
  bf16*  xn    = (bf16*) alloc((size_t)BL*BDIM*2);
  float* skip  = (float*)alloc((size_t)BL*EDIM*4);
  float* xi    = (float*)alloc((size_t)BL*EDIM*4);   // later reused as y
  float* xc    = (float*)alloc((size_t)BL*EDIM*4);
  float* dlt   = (float*)alloc((size_t)BL*EDIM*4);   // delta_pre/delta, later dresid
  bf16*  d1    = (bf16*) alloc((size_t)BL*DDPAD*2);
  bf16*  w2p   = (bf16*) alloc((size_t)EDIM*DDPAD*2);
  float* Bm    = (float*)alloc((size_t)BL*NST*4);
  float* Cm    = (float*)alloc((size_t)BL*NST*4);
  bf16*  y2    = (bf16*) alloc((size_t)BL*EDIM*2);
  float* Pbuf  = (float*)alloc((size_t)CCH*BEN*4);   // chunk scan: products
  float* Hbuf  = (float*)alloc((size_t)CCH*BEN*4);   // chunk scan: local end states
  float* Hin   = (float*)alloc((size_t)CCH*BEN*4);   // chunk scan: corrected inputs
  bf16*  wcvt  = (bf16*) alloc((size_t)VOCAB*BDIM*2);  // bf16 weight staging (reused)

  dim3 blk(256);
  const int nED = EDIM*BDIM/256;    // grid for E*D-sized converts (divides exactly)
  const int scanGrid = BB*CCH*(EDIM/16);   // 3072 blocks
  k_embed<<<BL*BDIM/256, blk, 0, stream>>>(tokens, emb, resid);
  for (int l = 0; l < NLAYERS; l++) {
    k_rmsnorm<<<BL, blk, 0, stream>>>(resid, norm_w + (size_t)l*BDIM, xn);

    k_cvt<<<nED, blk, 0, stream>>>(skip_w + (size_t)l*EDIM*BDIM, wcvt);
    k_gemm<false><<<dim3(EDIM/128, BL/128), blk, 0, stream>>>(xn, wcvt, skip, EDIM, BDIM);

    k_cvt<<<nED, blk, 0, stream>>>(in_w + (size_t)l*EDIM*BDIM, wcvt);
    k_gemm<false><<<dim3(EDIM/128, BL/128), blk, 0, stream>>>(xn, wcvt, xi, EDIM, BDIM);

    k_conv<<<BL*EDIM/256, blk, 0, stream>>>(
        xi, conv_w + (size_t)l*EDIM*DCONV, conv_b + (size_t)l*EDIM, xc);
    k_d1<<<BL, blk, 0, stream>>>(xc, Wd1 + (size_t)l*DDELTA*EDIM, d1);
    k_padw<<<EDIM*DDPAD/256, blk, 0, stream>>>(Wd2w + (size_t)l*EDIM*DDELTA, w2p);
    k_gemm<false><<<dim3(EDIM/128, BL/128), blk, 0, stream>>>(d1, w2p, dlt, EDIM, DDPAD);
    k_softplus<<<BL*EDIM/256, blk, 0, stream>>>(dlt, Wd2b + (size_t)l*EDIM);
    k_bc<<<BL, blk, 0, stream>>>(xc, WBw + (size_t)l*NST*EDIM, WCw + (size_t)l*NST*EDIM, Bm, Cm);

    // chunked scan (replaces monolithic k_scan): y -> xi buffer
    k_scan1<<<scanGrid, blk, 0, stream>>>(dlt, xc, Bm,
        A_log + (size_t)l*EDIM*NST, Pbuf, Hbuf);
    k_scanfix<<<BEN/256, blk, 0, stream>>>(Pbuf, Hbuf, Hin);
    k_scan2<<<scanGrid, blk, 0, stream>>>(dlt, xc, Bm, Cm,
        A_log + (size_t)l*EDIM*NST, Hin, xi);

    k_ymix<<<BL*EDIM/256, blk, 0, stream>>>(xi, xc, skip, W_D + (size_t)l*EDIM, y2);

    k_cvt<<<nED, blk, 0, stream>>>(out_w + (size_t)l*BDIM*EDIM, wcvt);
    k_gemm<false><<<dim3(BDIM/128, BL/128), blk, 0, stream>>>(
        y2, wcvt, dlt, BDIM, EDIM);                              // dresid -> dlt buffer
    k_add<<<BL*BDIM/256, blk, 0, stream>>>(resid, dlt);
  }
  k_rmsnorm<<<BL, blk, 0, stream>>>(resid, fnw, xn);
  k_cvt<<<VOCAB*BDIM/256, blk, 0, stream>>>(lm_w, wcvt);
  k_gemm<false><<<dim3((VOCAB+127)/128, BL/128), blk, 0, stream>>>(
      xn, wcvt, out, VOCAB, BDIM);
}

// Round 2
// 1664.232 us; speedup vs baseline: 1.3868x; 1.0014x over previous
//
#include <hip/hip_runtime.h>
#include <hip/hip_bf16.h>

// ---- problem dims ----
#define BB     2
#define LL     1024
#define BL     (BB*LL)      // 2048 rows
#define BDIM   768
#define EDIM   1536
#define NST    16
#define DDELTA 48
#define DDPAD  64
#define DCONV  4
#define VOCAB  50280
#define NLAYERS 2

// ---- chunked scan params ----
#define CCH    16                 // chunks over L
#define TCH    (LL/CCH)           // 64 steps per chunk
#define BEN    (BB*EDIM*NST)      // 49152 recurrence lanes

typedef __hip_bfloat16 bf16;
typedef short short8 __attribute__((ext_vector_type(8)));
typedef float floatx4 __attribute__((ext_vector_type(4)));

static __device__ __forceinline__ float bf2f(bf16 v){ return __bfloat162float(v); }
static __device__ __forceinline__ bf16  f2bf(float v){ return __float2bfloat16(v); }

// async global->LDS, 16B per lane; LDS dest = wave-uniform base + lane*16
typedef const __attribute__((address_space(1))) unsigned int gu32;
typedef __attribute__((address_space(3))) unsigned int lu32;
static __device__ __forceinline__ void glds16(const bf16* g, bf16* l) {
  __builtin_amdgcn_global_load_lds((gu32*)g, (lu32*)l, 16, 0, 0);
}

// ---- fp32 -> bf16 conversion (for MFMA weight operands) ----
__global__ void k_cvt(const float* __restrict__ src, bf16* __restrict__ dst) {
  int idx = blockIdx.x*256 + threadIdx.x;
  dst[idx] = f2bf(src[idx]);
}

// ---- embedding gather: resid[bl,d] = emb[tok[bl],d] ----
__global__ void k_embed(const int* __restrict__ tok, const float* __restrict__ emb,
                        float* __restrict__ resid) {
  int idx = blockIdx.x*256 + threadIdx.x;       // BL*BDIM total, exact
  int bl = idx / BDIM, d = idx % BDIM;
  resid[idx] = emb[(size_t)tok[bl]*BDIM + d];
}

// ---- rmsnorm row kernel: out_bf16[m,:] = resid[m,:]*rsqrt(mean sq + 1e-5)*w ----
__global__ __launch_bounds__(256) void k_rmsnorm(const float* __restrict__ resid,
                        const float* __restrict__ w, bf16* __restrict__ out) {
  int m = blockIdx.x, tid = threadIdx.x;
  const float* row = resid + (size_t)m*BDIM;
  float ss = 0.f;
  for (int d = tid; d < BDIM; d += 256) { float v = row[d]; ss += v*v; }
  for (int off = 32; off; off >>= 1) ss += __shfl_down(ss, off);
  __shared__ float red[4];
  if ((tid & 63) == 0) red[tid>>6] = ss;
  __syncthreads();
  float rstd = rsqrtf((red[0]+red[1]+red[2]+red[3]) / (float)BDIM + 1e-5f);
  for (int d = tid; d < BDIM; d += 256)
    out[(size_t)m*BDIM + d] = f2bf(row[d]*rstd*w[d]);
}

// ---- MFMA GEMM: C[M,N] = A[M,K](bf16) @ W[N,K](bf16)^T ----
// 128x128 tile, 256 thr = 4 waves (2x2 of 64x64), BK=32, 16x16x32 bf16 MFMA.
// m97 structure: global_load_lds width-16 staging (no VGPR roundtrip) +
// bijective XCD-aware block swizzle, M-fastest logical order (W-panel L2 reuse).
// W rows clamped to N-1 (reads valid mem), stores masked n<N.
template<bool OUT_BF16>
__global__ __launch_bounds__(256) void k_gemm(const bf16* __restrict__ A,
      const bf16* __restrict__ W, void* __restrict__ Cp, int N, int K) {
  __shared__ alignas(16) bf16 As[128*32];
  __shared__ alignas(16) bf16 Bs[128*32];
  // XCD swizzle: hw assigns orig%8 -> XCD; give each XCD a contiguous logical
  // chunk (bijective also when nwg%8 != 0). Logical order: M-block fastest.
  const int nwg = gridDim.x * gridDim.y;
  const int orig = blockIdx.y * gridDim.x + blockIdx.x;
  const int qq = nwg >> 3, rr = nwg & 7;
  const int xcd = orig & 7, sub = orig >> 3;
  const int logical = (xcd < rr ? xcd*(qq+1) : rr*(qq+1) + (xcd-rr)*qq) + sub;
  const int by = logical % gridDim.y;           // M-block (fastest -> W reuse)
  const int bx = logical / gridDim.y;           // N-block
  const int m0 = by * 128, n0 = bx * 128;

  const int tid = threadIdx.x, lane = tid & 63, wave = tid >> 6;
  const int wm = (wave >> 1) * 64, wn = (wave & 1) * 64;
  const int mr = lane & 15, q = lane >> 4;      // fragment lane decomposition
  floatx4 acc[4][4] = {};

  // staging: each wave owns 16 rows (64 lanes = 16 rows x 4 16B-chunks)
  const int sr = lane >> 2, ch = lane & 3;
  const int wbase = wave * 16;
  int wr0 = n0 + wbase + sr;      if (wr0 >= N) wr0 = N - 1;
  int wr1 = n0 + 64 + wbase + sr; if (wr1 >= N) wr1 = N - 1;
  const bf16* Ar0 = A + (size_t)(m0 + wbase + sr)*K      + ch*8;
  const bf16* Ar1 = A + (size_t)(m0 + 64 + wbase + sr)*K + ch*8;
  const bf16* Wr0 = W + (size_t)wr0*K + ch*8;
  const bf16* Wr1 = W + (size_t)wr1*K + ch*8;
  bf16* lA0 = As + wbase*32;          // +lane*16B implicit
  bf16* lA1 = As + (64 + wbase)*32;
  bf16* lB0 = Bs + wbase*32;
  bf16* lB1 = Bs + (64 + wbase)*32;

  for (int k0 = 0; k0 < K; k0 += 32) {
    __syncthreads();     // previous iter's ds_reads done before overwrite
    glds16(Ar0 + k0, lA0);
    glds16(Ar1 + k0, lA1);
    glds16(Wr0 + k0, lB0);
    glds16(Wr1 + k0, lB1);
    asm volatile("s_waitcnt vmcnt(0)" ::: "memory");
    __syncthreads();
    short8 af[4], bfr[4];
    #pragma unroll
    for (int i = 0; i < 4; i++)
      af[i]  = *reinterpret_cast<const short8*>(&As[(wm + i*16 + mr)*32 + q*8]);
    #pragma unroll
    for (int j = 0; j < 4; j++)
      bfr[j] = *reinterpret_cast<const short8*>(&Bs[(wn + j*16 + mr)*32 + q*8]);
    #pragma unroll
    for (int i = 0; i < 4; i++)
      #pragma unroll
      for (int j = 0; j < 4; j++)
        acc[i][j] = __builtin_amdgcn_mfma_f32_16x16x32_bf16(af[i], bfr[j], acc[i][j], 0, 0, 0);
  }
  // epilogue: C/D layout col=lane&15, row=quad*4+reg
  #pragma unroll
  for (int i = 0; i < 4; i++)
    #pragma unroll
    for (int j = 0; j < 4; j++)
      #pragma unroll
      for (int rg = 0; rg < 4; rg++) {
        int m = m0 + wm + i*16 + q*4 + rg;
        int n = n0 + wn + j*16 + mr;
        if (n < N) {
          float v = acc[i][j][rg];
          if (OUT_BF16) ((bf16*)Cp)[(size_t)m*N + n] = f2bf(v);
          else          ((float*)Cp)[(size_t)m*N + n] = v;
        }
      }
}

// ---- depthwise causal conv (k=4) + bias + silu ----
__global__ void k_conv(const float* __restrict__ xi, const float* __restrict__ cw,
                       const float* __restrict__ cb, float* __restrict__ xc) {
  int idx = blockIdx.x*256 + threadIdx.x;       // BL*EDIM, exact
  int e = idx % EDIM, bl = idx / EDIM, l = bl % LL;
  float acc = cb[e];
  #pragma unroll
  for (int k = 0; k < DCONV; k++) {
    int ls = l - (DCONV-1) + k;
    if (ls >= 0) acc += xi[(size_t)(bl + ls - l)*EDIM + e] * cw[e*DCONV + k];
  }
  xc[idx] = acc / (1.f + expf(-acc));
}

// ---- skinny GEMM: d1[m,0:64] = xc[m,:] @ Wd1[48,E]^T  (cols 48..63 = 0), bf16 out ----
__global__ __launch_bounds__(256) void k_d1(const float* __restrict__ xc,
      const float* __restrict__ wd1, bf16* __restrict__ d1) {
  int m = blockIdx.x, tid = threadIdx.x;
  __shared__ float xrow[EDIM];
  for (int k = tid; k < EDIM; k += 256) xrow[k] = xc[(size_t)m*EDIM + k];
  __syncthreads();
  int wave = tid >> 6, lane = tid & 63;
  for (int n = wave; n < DDPAD; n += 4) {
    float s = 0.f;
    if (n < DDELTA) {
      const float* wr = wd1 + (size_t)n*EDIM;
      for (int k = lane; k < EDIM; k += 64) s += xrow[k]*wr[k];
      for (int off = 32; off; off >>= 1) s += __shfl_down(s, off);
    }
    if (lane == 0) d1[(size_t)m*DDPAD + n] = f2bf(s);
  }
}

// ---- pad + cvt Wd2 [E,48] fp32 -> [E,64] bf16 ----
__global__ void k_padw(const float* __restrict__ wsrc, bf16* __restrict__ wp) {
  int idx = blockIdx.x*256 + threadIdx.x;       // EDIM*64
  int e = idx >> 6, cc = idx & 63;
  wp[idx] = (cc < DDELTA) ? f2bf(wsrc[(size_t)e*DDELTA + cc]) : f2bf(0.f);
}

// ---- softplus(x + b[e]) in place ----
__global__ void k_softplus(float* __restrict__ d, const float* __restrict__ b) {
  int idx = blockIdx.x*256 + threadIdx.x;       // BL*EDIM
  int e = idx % EDIM;
  float v = d[idx] + b[e];
  d[idx] = fmaxf(v, 0.f) + log1pf(expf(-fabsf(v)));
}

// ---- skinny GEMM: Bm/Cm[m,0:16] = xc[m,:] @ {WB,WC}[16,E]^T ----
__global__ __launch_bounds__(256) void k_bc(const float* __restrict__ xc,
    const float* __restrict__ wb, const float* __restrict__ wc,
    float* __restrict__ Bm, float* __restrict__ Cm) {
  int m = blockIdx.x, tid = threadIdx.x;
  __shared__ float xrow[EDIM];
  for (int k = tid; k < EDIM; k += 256) xrow[k] = xc[(size_t)m*EDIM + k];
  __syncthreads();
  int wave = tid >> 6, lane = tid & 63;
  for (int n = wave; n < 32; n += 4) {
    const float* wr = (n < NST) ? wb + (size_t)n*EDIM : wc + (size_t)(n-NST)*EDIM;
    float s = 0.f;
    for (int k = lane; k < EDIM; k += 64) s += xrow[k]*wr[k];
    for (int off = 32; off; off >>= 1) s += __shfl_down(s, off);
    if (lane == 0) {
      if (n < NST) Bm[(size_t)m*NST + n]       = s;
      else         Cm[(size_t)m*NST + (n-NST)] = s;
    }
  }
}

// ---- chunked selective scan ----
// Recurrence h_t = a_t h_{t-1} + b_t (a_t = exp(delta_t*A[e,n])) is associative.
// pass1 scans each chunk from h=0 emitting (P = prod a_t, H = local end state);
// tiny serial fix-up combines chunk carries; pass2 rescans from true h_in.

__global__ __launch_bounds__(256) void k_scan1(const float* __restrict__ delta,
    const float* __restrict__ xc, const float* __restrict__ Bm,
    const float* __restrict__ a_log, float* __restrict__ Pbuf,
    float* __restrict__ Hbuf) {
  int tid = threadIdx.x;
  int n = tid & 15, el = tid >> 4;
  int bx = blockIdx.x;
  int et = bx % (EDIM/16); bx /= (EDIM/16);
  int c = bx % CCH, b = bx / CCH;
  int e = et*16 + el;
  float Aen = -__expf(a_log[(size_t)e*NST + n]);
  const float* dp = delta + ((size_t)b*LL + (size_t)c*TCH)*EDIM + e;
  const float* xp = xc    + ((size_t)b*LL + (size_t)c*TCH)*EDIM + e;
  const float* bp = Bm    + ((size_t)b*LL + (size_t)c*TCH)*NST + n;
  float h = 0.f, p = 1.f;
  #pragma unroll 4
  for (int t = 0; t < TCH; t++) {
    float dl = dp[(size_t)t*EDIM];
    float xv = xp[(size_t)t*EDIM];
    float bv = bp[t*NST];
    float a = __expf(dl*Aen);
    h = a*h + dl*bv*xv;
    p *= a;
  }
  size_t ben = ((size_t)b*EDIM + e)*NST + n;
  Pbuf[(size_t)c*BEN + ben] = p;
  Hbuf[(size_t)c*BEN + ben] = h;
}

__global__ __launch_bounds__(256) void k_scanfix(const float* __restrict__ Pbuf,
    const float* __restrict__ Hbuf, float* __restrict__ Hin) {
  int ben = blockIdx.x*256 + threadIdx.x;       // BEN total, exact
  float h = 0.f;
  #pragma unroll
  for (int c = 0; c < CCH; c++) {
    Hin[(size_t)c*BEN + ben] = h;
    h = Pbuf[(size_t)c*BEN + ben]*h + Hbuf[(size_t)c*BEN + ben];
  }
}

__global__ __launch_bounds__(256) void k_scan2(const float* __restrict__ delta,
    const float* __restrict__ xc, const float* __restrict__ Bm,
    const float* __restrict__ Cm, const float* __restrict__ a_log,
    const float* __restrict__ Hin, float* __restrict__ y) {
  int tid = threadIdx.x;
  int n = tid & 15, el = tid >> 4;
  int bx = blockIdx.x;
  int et = bx % (EDIM/16); bx /= (EDIM/16);
  int c = bx % CCH, b = bx / CCH;
  int e = et*16 + el;
  float Aen = -__expf(a_log[(size_t)e*NST + n]);
  const float* dp = delta + ((size_t)b*LL + (size_t)c*TCH)*EDIM + e;
  const float* xp = xc    + ((size_t)b*LL + (size_t)c*TCH)*EDIM + e;
  const float* bp = Bm    + ((size_t)b*LL + (size_t)c*TCH)*NST + n;
  const float* cp = Cm    + ((size_t)b*LL + (size_t)c*TCH)*NST + n;
  float* yp = y + ((size_t)b*LL + (size_t)c*TCH)*EDIM + e;
  size_t ben = ((size_t)b*EDIM + e)*NST + n;
  float h = Hin[(size_t)c*BEN + ben];
  #pragma unroll 4
  for (int t = 0; t < TCH; t++) {
    float dl = dp[(size_t)t*EDIM];
    float xv = xp[(size_t)t*EDIM];
    float bv = bp[t*NST];
    float cv = cp[t*NST];
    h = __expf(dl*Aen)*h + dl*bv*xv;
    float p = h*cv;
    p += __shfl_xor(p, 1); p += __shfl_xor(p, 2);
    p += __shfl_xor(p, 4); p += __shfl_xor(p, 8);
    if (n == 0) yp[(size_t)t*EDIM] = p;
  }
}

// ---- y2 = (y + xc*wd[e]) * silu(skip), bf16 out ----
__global__ void k_ymix(const float* __restrict__ y, const float* __restrict__ xc,
    const float* __restrict__ skip, const float* __restrict__ wd, bf16* __restrict__ y2) {
  int idx = blockIdx.x*256 + threadIdx.x;       // BL*EDIM
  int e = idx % EDIM;
  float s = skip[idx];
  y2[idx] = f2bf((y[idx] + xc[idx]*wd[e]) * (s / (1.f + expf(-s))));
}

// ---- resid += d ----
__global__ void k_add(float* __restrict__ resid, const float* __restrict__ d) {
  int idx = blockIdx.x*256 + threadIdx.x;
  resid[idx] += d[idx];
}

extern "C" void kernel_launch(void* const* d_in, const int* in_sizes, int n_in,
                              void* d_out, int out_size, void* d_ws, size_t ws_size,
                              hipStream_t stream) {
  const int*   tokens = (const int*)  d_in[0];
  const float* emb    = (const float*)d_in[1];
  const float* norm_w = (const float*)d_in[2];
  const float* skip_w = (const float*)d_in[3];
  const float* in_w   = (const float*)d_in[4];
  const float* conv_w = (const float*)d_in[5];
  const float* conv_b = (const float*)d_in[6];
  const float* Wd1    = (const float*)d_in[7];
  const float* Wd2w   = (const float*)d_in[8];
  const float* Wd2b   = (const float*)d_in[9];
  const float* WBw    = (const float*)d_in[10];
  const float* WCw    = (const float*)d_in[11];
  const float* A_log  = (const float*)d_in[12];
  const float* W_D    = (const float*)d_in[13];
  const float* out_w  = (const float*)d_in[14];
  const float* fnw    = (const float*)d_in[15];
  const float* lm_w   = (const float*)d_in[16];
  float* out = (float*)d_out;

  // workspace layout (256B-aligned chunks)
  char* wsp = (char*)d_ws;
  auto alloc = [&](size_t bytes) { char* p = wsp; wsp += (bytes + 255) & ~(size_t)255; return p; };
  float* resid = (float*)alloc((size_t)BL*BDIM*4);
  bf16*  xn    = (bf16*) alloc((size_t)BL*BDIM*2);
  float* skip  = (float*)alloc((size_t)BL*EDIM*4);
  float* xi    = (float*)alloc((size_t)BL*EDIM*4);   // later reused as y
  float* xc    = (float*)alloc((size_t)BL*EDIM*4);
  float* dlt   = (float*)alloc((size_t)BL*EDIM*4);   // delta_pre/delta, later dresid
  bf16*  d1    = (bf16*) alloc((size_t)BL*DDPAD*2);
  bf16*  w2p   = (bf16*) alloc((size_t)EDIM*DDPAD*2);
  float* Bm    = (float*)alloc((size_t)BL*NST*4);
  float* Cm    = (float*)alloc((size_t)BL*NST*4);
  bf16*  y2    = (bf16*) alloc((size_t)BL*EDIM*2);
  float* Pbuf  = (float*)alloc((size_t)CCH*BEN*4);   // chunk scan: products
  float* Hbuf  = (float*)alloc((size_t)CCH*BEN*4);   // chunk scan: local end states
  float* Hin   = (float*)alloc((size_t)CCH*BEN*4);   // chunk scan: corrected inputs
  bf16*  wcvt  = (bf16*) alloc((size_t)VOCAB*BDIM*2);  // bf16 weight staging (reused)

  dim3 blk(256);
  const int nED = EDIM*BDIM/256;    // grid for E*D-sized converts (divides exactly)
  const int scanGrid = BB*CCH*(EDIM/16);   // 3072 blocks
  k_embed<<<BL*BDIM/256, blk, 0, stream>>>(tokens, emb, resid);
  for (int l = 0; l < NLAYERS; l++) {
    k_rmsnorm<<<BL, blk, 0, stream>>>(resid, norm_w + (size_t)l*BDIM, xn);

    k_cvt<<<nED, blk, 0, stream>>>(skip_w + (size_t)l*EDIM*BDIM, wcvt);
    k_gemm<false><<<dim3(EDIM/128, BL/128), blk, 0, stream>>>(xn, wcvt, skip, EDIM, BDIM);

    k_cvt<<<nED, blk, 0, stream>>>(in_w + (size_t)l*EDIM*BDIM, wcvt);
    k_gemm<false><<<dim3(EDIM/128, BL/128), blk, 0, stream>>>(xn, wcvt, xi, EDIM, BDIM);

    k_conv<<<BL*EDIM/256, blk, 0, stream>>>(
        xi, conv_w + (size_t)l*EDIM*DCONV, conv_b + (size_t)l*EDIM, xc);
    k_d1<<<BL, blk, 0, stream>>>(xc, Wd1 + (size_t)l*DDELTA*EDIM, d1);
    k_padw<<<EDIM*DDPAD/256, blk, 0, stream>>>(Wd2w + (size_t)l*EDIM*DDELTA, w2p);
    k_gemm<false><<<dim3(EDIM/128, BL/128), blk, 0, stream>>>(d1, w2p, dlt, EDIM, DDPAD);
    k_softplus<<<BL*EDIM/256, blk, 0, stream>>>(dlt, Wd2b + (size_t)l*EDIM);
    k_bc<<<BL, blk, 0, stream>>>(xc, WBw + (size_t)l*NST*EDIM, WCw + (size_t)l*NST*EDIM, Bm, Cm);

    // chunked scan: y -> xi buffer
    k_scan1<<<scanGrid, blk, 0, stream>>>(dlt, xc, Bm,
        A_log + (size_t)l*EDIM*NST, Pbuf, Hbuf);
    k_scanfix<<<BEN/256, blk, 0, stream>>>(Pbuf, Hbuf, Hin);
    k_scan2<<<scanGrid, blk, 0, stream>>>(dlt, xc, Bm, Cm,
        A_log + (size_t)l*EDIM*NST, Hin, xi);

    k_ymix<<<BL*EDIM/256, blk, 0, stream>>>(xi, xc, skip, W_D + (size_t)l*EDIM, y2);

    k_cvt<<<nED, blk, 0, stream>>>(out_w + (size_t)l*BDIM*EDIM, wcvt);
    k_gemm<false><<<dim3(BDIM/128, BL/128), blk, 0, stream>>>(
        y2, wcvt, dlt, BDIM, EDIM);                              // dresid -> dlt buffer
    k_add<<<BL*BDIM/256, blk, 0, stream>>>(resid, dlt);
  }
  k_rmsnorm<<<BL, blk, 0, stream>>>(resid, fnw, xn);
  k_cvt<<<VOCAB*BDIM/256, blk, 0, stream>>>(lm_w, wcvt);
  k_gemm<false><<<dim3((VOCAB+127)/128, BL/128), blk, 0, stream>>>(
      xn, wcvt, out, VOCAB, BDIM);
}